// Round 3
// baseline (136.957 us; speedup 1.0000x reference)
//
#include <hip/hip_runtime.h>

// out = mean_i( rank_of_diag(cos_sim(x1,x2))_i < nper ), nper = S/100+1.
// fp16x3 (Markidis) MFMA GEMM-count. R3: pre-convert x1/x2 to fragment-major
// fp16 hi/lo arrays in global memory; count kernel loads fragments directly
// (coalesced dwordx4, no LDS staging, no K-loop barriers).
//
// Fragment layout (HW-verified via R2 pass): A-operand of mfma_f32_32x32x16_f16:
// lane l holds row=(l&31), k=(l>>5)*8+j, j=0..7. Frag array: per (rowgroup rg,
// k16-group s): [hi 512 halves][lo 512 halves], half-offset ((rg*8+s)*2+p)*512 + l*8.

#define KDIM 128

typedef _Float16 half8 __attribute__((ext_vector_type(8)));
typedef float floatx16 __attribute__((ext_vector_type(16)));

// ---------- Kernel 1: convert to frag-major hi/lo + norms + thr + zero counts ----------
// one wave per 32-row group (B == S assumed; guarded in kernel_launch)
__global__ __launch_bounds__(64) void convert_kernel(
    const float* __restrict__ x1, const float* __restrict__ x2,
    _Float16* __restrict__ AF, _Float16* __restrict__ BF,
    float* __restrict__ invn, float* __restrict__ thr,
    int* __restrict__ row_count)
{
    const int rg   = blockIdx.x;
    const int lane = threadIdx.x;
    const int r    = rg * 32 + (lane & 31);
    const int h    = lane >> 5;

    float s22 = 0.f, s12 = 0.f;
    #pragma unroll
    for (int s = 0; s < 8; s++) {
        const float* p1 = &x1[(size_t)r * KDIM + s * 16 + h * 8];
        const float* p2 = &x2[(size_t)r * KDIM + s * 16 + h * 8];
        float v1[8], v2[8];
        *(float4*)&v1[0] = *(const float4*)p1;
        *(float4*)&v1[4] = *(const float4*)(p1 + 4);
        *(float4*)&v2[0] = *(const float4*)p2;
        *(float4*)&v2[4] = *(const float4*)(p2 + 4);
        half8 h1, l1, h2, l2;
        #pragma unroll
        for (int j = 0; j < 8; j++) {
            _Float16 a = (_Float16)v1[j];
            h1[j] = a; l1[j] = (_Float16)(v1[j] - (float)a);
            _Float16 b = (_Float16)v2[j];
            h2[j] = b; l2[j] = (_Float16)(v2[j] - (float)b);
            s22 = fmaf(v2[j], v2[j], s22);
            s12 = fmaf(v1[j], v2[j], s12);
        }
        const int off = (rg * 8 + s) * 1024 + lane * 8;   // halves
        *(half8*)&AF[off]       = h1;
        *(half8*)&AF[off + 512] = l1;
        *(half8*)&BF[off]       = h2;
        *(half8*)&BF[off + 512] = l2;
    }
    s22 += __shfl_xor(s22, 32);
    s12 += __shfl_xor(s12, 32);
    if (lane < 32) {
        const float iv = rsqrtf(s22);
        invn[r] = iv;
        thr[r]  = s12 * iv;
        row_count[r] = 0;
    }
}

// ---------- Kernel 2: barrier-free MFMA GEMM + compare-count ----------
// 128x128 block tile, 4 waves in 2x2, each wave 64x64 (2x2 of 32x32), K=128.
__global__ __launch_bounds__(256) void count_kernel(
    const _Float16* __restrict__ AF, const _Float16* __restrict__ BF,
    const float* __restrict__ invn, const float* __restrict__ thr,
    int* __restrict__ row_count)
{
    __shared__ float s_thr[128], s_invn[128];
    __shared__ int cnt_s[128];

    const int tid  = threadIdx.x;
    const int wave = tid >> 6;
    const int lane = tid & 63;
    const int row0 = blockIdx.y * 128;
    const int col0 = blockIdx.x * 128;
    const int wr = (wave >> 1) * 64;
    const int wc = (wave & 1) * 64;

    if (tid < 128) {
        cnt_s[tid]  = 0;
        s_thr[tid]  = thr[row0 + tid];
        s_invn[tid] = invn[col0 + tid];
    }
    __syncthreads();

    const int arg = (row0 + wr) >> 5;   // global rowgroup base for this wave
    const int brg = (col0 + wc) >> 5;
    const _Float16* abase = AF + (size_t)arg * 8 * 1024 + lane * 8;
    const _Float16* bbase = BF + (size_t)brg * 8 * 1024 + lane * 8;

    floatx16 acc[2][2];
    #pragma unroll
    for (int a = 0; a < 2; a++)
        #pragma unroll
        for (int b = 0; b < 2; b++)
            #pragma unroll
            for (int i = 0; i < 16; i++) acc[a][b][i] = 0.f;

    #pragma unroll
    for (int s = 0; s < 8; s++) {
        half8 ah[2], al[2], bh[2], bl[2];
        #pragma unroll
        for (int t = 0; t < 2; t++) {
            const _Float16* pa = abase + (t * 8 + s) * 1024;
            ah[t] = *(const half8*)pa;
            al[t] = *(const half8*)(pa + 512);
            const _Float16* pb = bbase + (t * 8 + s) * 1024;
            bh[t] = *(const half8*)pb;
            bl[t] = *(const half8*)(pb + 512);
        }
        #pragma unroll
        for (int mt = 0; mt < 2; mt++)
            #pragma unroll
            for (int nt = 0; nt < 2; nt++) {
                acc[mt][nt] = __builtin_amdgcn_mfma_f32_32x32x16_f16(al[mt], bh[nt], acc[mt][nt], 0, 0, 0);
                acc[mt][nt] = __builtin_amdgcn_mfma_f32_32x32x16_f16(ah[mt], bl[nt], acc[mt][nt], 0, 0, 0);
                acc[mt][nt] = __builtin_amdgcn_mfma_f32_32x32x16_f16(ah[mt], bh[nt], acc[mt][nt], 0, 0, 0);
            }
    }

    // epilogue (verified in R2): C/D 32x32: col=lane&31, row=(reg&3)+8*(reg>>2)+4*(lane>>5)
    const int cm = lane & 31;
    const int hw = lane >> 5;
    const float iv0 = s_invn[wc + cm];
    const float iv1 = s_invn[wc + 32 + cm];
    const int gc0 = col0 + wc + cm;
    const int gc1 = gc0 + 32;

    #pragma unroll
    for (int mt = 0; mt < 2; mt++) {
        #pragma unroll
        for (int reg = 0; reg < 16; reg++) {
            const int rbase = wr + mt * 32 + (reg & 3) + 8 * (reg >> 2);
            const int rloc  = rbase + 4 * hw;
            const int grow  = row0 + rloc;
            const float t   = s_thr[rloc];
            const bool p0 = (acc[mt][0][reg] * iv0 > t) && (gc0 != grow);
            const bool p1 = (acc[mt][1][reg] * iv1 > t) && (gc1 != grow);
            const unsigned long long b0 = __ballot(p0);
            const unsigned long long b1 = __ballot(p1);
            if (lane == 0) {
                const int clo = __popcll(b0 & 0xffffffffULL) + __popcll(b1 & 0xffffffffULL);
                if (clo) atomicAdd(&cnt_s[rbase], clo);
            } else if (lane == 32) {
                const int chi = __popcll(b0 >> 32) + __popcll(b1 >> 32);
                if (chi) atomicAdd(&cnt_s[rbase + 4], chi);
            }
        }
    }
    __syncthreads();
    if (tid < 128) {
        const int v = cnt_s[tid];
        if (v) atomicAdd(&row_count[row0 + tid], v);
    }
}

// ---------- Fallback path (R2, LDS-staged, ws-light) ----------
__global__ __launch_bounds__(256) void prep_kernel_fb(
    const float* __restrict__ x1, const float* __restrict__ x2,
    float* __restrict__ invn, float* __restrict__ thr,
    int* __restrict__ row_count, int B, int S)
{
    const int wave = threadIdx.x >> 6;
    const int lane = threadIdx.x & 63;
    const int row = blockIdx.x * 4 + wave;
    if (row >= S && row >= B) return;
    float s22 = 0.f, s12 = 0.f;
    if (row < S) {
        const float2* p1 = (const float2*)&x1[(size_t)row * KDIM];
        const float2* p2 = (const float2*)&x2[(size_t)row * KDIM];
        float2 a = p1[lane];
        float2 b = p2[lane];
        s22 = fmaf(b.x, b.x, b.y * b.y);
        s12 = fmaf(a.x, b.x, a.y * b.y);
    }
    #pragma unroll
    for (int m = 32; m > 0; m >>= 1) { s22 += __shfl_xor(s22, m); s12 += __shfl_xor(s12, m); }
    if (lane == 0) {
        if (row < S) {
            float iv = rsqrtf(s22);
            invn[row] = iv;
            if (row < B) thr[row] = s12 * iv;
        }
        if (row < B) row_count[row] = 0;
    }
}

__global__ __launch_bounds__(256) void count_kernel_fb(
    const float* __restrict__ x1, const float* __restrict__ x2,
    const float* __restrict__ invn, const float* __restrict__ thr,
    int* __restrict__ row_count)
{
    __shared__ __align__(16) _Float16 As_hi[4096], As_lo[4096];
    __shared__ __align__(16) _Float16 Bs_hi[4096], Bs_lo[4096];
    __shared__ float s_thr[128], s_invn[128];
    __shared__ int cnt_s[128];
    const int tid  = threadIdx.x;
    const int wave = tid >> 6;
    const int lane = tid & 63;
    const int row0 = blockIdx.y * 128;
    const int col0 = blockIdx.x * 128;
    const int wr = (wave >> 1) * 64;
    const int wc = (wave & 1) * 64;
    if (tid < 128) { cnt_s[tid] = 0; s_thr[tid] = thr[row0 + tid]; s_invn[tid] = invn[col0 + tid]; }
    floatx16 acc[2][2];
    #pragma unroll
    for (int a = 0; a < 2; a++)
        #pragma unroll
        for (int b = 0; b < 2; b++)
            #pragma unroll
            for (int i = 0; i < 16; i++) acc[a][b][i] = 0.f;
    const int sr   = tid >> 1;
    const int sks2 = tid & 1;
    const int wbase = ((sr >> 5) * 2 + sks2) * 512 + (sr & 31) * 8;
    const size_t ga = (size_t)(row0 + sr) * KDIM + sks2 * 16;
    const size_t gb = (size_t)(col0 + sr) * KDIM + sks2 * 16;
    const int wrg = wr >> 5, wcg = wc >> 5, lane8 = lane * 8;
    for (int kc = 0; kc < KDIM; kc += 32) {
        __syncthreads();
        {
            const float* p = &x1[ga + kc];
            float v[16];
            *(float4*)&v[0] = *(const float4*)(p);     *(float4*)&v[4] = *(const float4*)(p + 4);
            *(float4*)&v[8] = *(const float4*)(p + 8); *(float4*)&v[12] = *(const float4*)(p + 12);
            half8 h0, h1, l0, l1;
            #pragma unroll
            for (int i = 0; i < 8; i++) {
                _Float16 h = (_Float16)v[i]; h0[i] = h; l0[i] = (_Float16)(v[i] - (float)h);
                _Float16 g = (_Float16)v[i + 8]; h1[i] = g; l1[i] = (_Float16)(v[i + 8] - (float)g);
            }
            *(half8*)&As_hi[wbase] = h0; *(half8*)&As_hi[wbase + 256] = h1;
            *(half8*)&As_lo[wbase] = l0; *(half8*)&As_lo[wbase + 256] = l1;
        }
        {
            const float* p = &x2[gb + kc];
            float v[16];
            *(float4*)&v[0] = *(const float4*)(p);     *(float4*)&v[4] = *(const float4*)(p + 4);
            *(float4*)&v[8] = *(const float4*)(p + 8); *(float4*)&v[12] = *(const float4*)(p + 12);
            half8 h0, h1, l0, l1;
            #pragma unroll
            for (int i = 0; i < 8; i++) {
                _Float16 h = (_Float16)v[i]; h0[i] = h; l0[i] = (_Float16)(v[i] - (float)h);
                _Float16 g = (_Float16)v[i + 8]; h1[i] = g; l1[i] = (_Float16)(v[i + 8] - (float)g);
            }
            *(half8*)&Bs_hi[wbase] = h0; *(half8*)&Bs_hi[wbase + 256] = h1;
            *(half8*)&Bs_lo[wbase] = l0; *(half8*)&Bs_lo[wbase + 256] = l1;
        }
        __syncthreads();
        #pragma unroll
        for (int ks2 = 0; ks2 < 2; ks2++) {
            half8 ah[2], al[2], bh[2], bl[2];
            #pragma unroll
            for (int t = 0; t < 2; t++) {
                const int oa = ((wrg + t) * 2 + ks2) * 512 + lane8;
                ah[t] = *(const half8*)&As_hi[oa]; al[t] = *(const half8*)&As_lo[oa];
                const int ob = ((wcg + t) * 2 + ks2) * 512 + lane8;
                bh[t] = *(const half8*)&Bs_hi[ob]; bl[t] = *(const half8*)&Bs_lo[ob];
            }
            #pragma unroll
            for (int mt = 0; mt < 2; mt++)
                #pragma unroll
                for (int nt = 0; nt < 2; nt++) {
                    acc[mt][nt] = __builtin_amdgcn_mfma_f32_32x32x16_f16(al[mt], bh[nt], acc[mt][nt], 0, 0, 0);
                    acc[mt][nt] = __builtin_amdgcn_mfma_f32_32x32x16_f16(ah[mt], bl[nt], acc[mt][nt], 0, 0, 0);
                    acc[mt][nt] = __builtin_amdgcn_mfma_f32_32x32x16_f16(ah[mt], bh[nt], acc[mt][nt], 0, 0, 0);
                }
        }
    }
    const int cm = lane & 31, hw = lane >> 5;
    const float iv0 = s_invn[wc + cm], iv1 = s_invn[wc + 32 + cm];
    const int gc0 = col0 + wc + cm, gc1 = gc0 + 32;
    #pragma unroll
    for (int mt = 0; mt < 2; mt++)
        #pragma unroll
        for (int reg = 0; reg < 16; reg++) {
            const int rbase = wr + mt * 32 + (reg & 3) + 8 * (reg >> 2);
            const int rloc  = rbase + 4 * hw;
            const int grow  = row0 + rloc;
            const float t   = s_thr[rloc];
            const bool p0 = (acc[mt][0][reg] * iv0 > t) && (gc0 != grow);
            const bool p1 = (acc[mt][1][reg] * iv1 > t) && (gc1 != grow);
            const unsigned long long b0 = __ballot(p0);
            const unsigned long long b1 = __ballot(p1);
            if (lane == 0) {
                const int clo = __popcll(b0 & 0xffffffffULL) + __popcll(b1 & 0xffffffffULL);
                if (clo) atomicAdd(&cnt_s[rbase], clo);
            } else if (lane == 32) {
                const int chi = __popcll(b0 >> 32) + __popcll(b1 >> 32);
                if (chi) atomicAdd(&cnt_s[rbase + 4], chi);
            }
        }
    __syncthreads();
    if (tid < 128) { const int v = cnt_s[tid]; if (v) atomicAdd(&row_count[row0 + tid], v); }
}

// ---------- Kernel 3: final reduction ----------
__global__ __launch_bounds__(1024) void finalize_kernel(
    const int* __restrict__ row_count, float* __restrict__ out, int B, int nper)
{
    __shared__ int wsum[16];
    const int t = threadIdx.x;
    int c = 0;
    for (int i = t; i < B; i += 1024) c += (row_count[i] < nper) ? 1 : 0;
    #pragma unroll
    for (int m = 32; m > 0; m >>= 1) c += __shfl_xor(c, m);
    if ((t & 63) == 0) wsum[t >> 6] = c;
    __syncthreads();
    if (t == 0) {
        int tot = 0;
        #pragma unroll
        for (int w = 0; w < 16; w++) tot += wsum[w];
        out[0] = (float)tot / (float)B;
    }
}

extern "C" void kernel_launch(void* const* d_in, const int* in_sizes, int n_in,
                              void* d_out, int out_size, void* d_ws, size_t ws_size,
                              hipStream_t stream)
{
    const float* x1 = (const float*)d_in[0];
    const float* x2 = (const float*)d_in[1];
    const int B = in_sizes[0] / KDIM;     // 8192
    const int S = in_sizes[1] / KDIM;     // 8192
    const int nper = S / 100 + 1;         // 82

    const size_t fragHalves = (size_t)S * KDIM * 2;           // hi+lo per operand
    const size_t needed = 2 * fragHalves * sizeof(_Float16)   // AF + BF (8 MB)
                        + (size_t)(2 * S + S) * sizeof(float) + (size_t)S * sizeof(int);

    if (B == S && (S % 128) == 0 && ws_size >= needed) {
        _Float16* AF = (_Float16*)d_ws;
        _Float16* BF = AF + fragHalves;
        float* invn      = (float*)(BF + fragHalves);
        float* thr       = invn + S;
        int*   row_count = (int*)(thr + S);

        convert_kernel<<<S / 32, 64, 0, stream>>>(x1, x2, AF, BF, invn, thr, row_count);
        dim3 grid(S / 128, B / 128);
        count_kernel<<<grid, 256, 0, stream>>>(AF, BF, invn, thr, row_count);
        finalize_kernel<<<1, 1024, 0, stream>>>(row_count, (float*)d_out, B, nper);
    } else {
        float* invn      = (float*)d_ws;
        float* thr       = invn + S;
        int*   row_count = (int*)(thr + B);
        const int mx = (B > S) ? B : S;
        prep_kernel_fb<<<(mx + 3) / 4, 256, 0, stream>>>(x1, x2, invn, thr, row_count, B, S);
        dim3 grid(S / 128, B / 128);
        count_kernel_fb<<<grid, 256, 0, stream>>>(x1, x2, invn, thr, row_count);
        finalize_kernel<<<1, 1024, 0, stream>>>(row_count, (float*)d_out, B, nper);
    }
}